// Round 7
// baseline (82661.603 us; speedup 1.0000x reference)
//
#include <hip/hip_runtime.h>
#include <hip/hip_bf16.h>

typedef unsigned short ushort_t;
typedef unsigned int uint_t;

// Problem constants (fixed shapes)
#define BB    32
#define SS    8192
#define DD    64
#define UU    32
#define GG    96        // 3U
#define NEDGE 500000
#define NVAR  50000
#define VOCAB 10000

// fp32 weight cache sub-layout
#define WT_KERN   0                         // [2][2][64][96] = 24576
#define WT_REC    24576                     // [2][2][32][96] = 12288
#define WT_BIAS   36864                     // [2][2][2][96]  = 768
#define WT_LW     37632                     // [64][64]       = 4096
#define WT_TOTAL  41728

// ws layout (float offsets). Total = 147,384,704 bytes ~= 140.6 MiB.
// W[0]=dtype flag, W[1]=selfchk0 maxdelta, W[2]=chkvar-consist, W[3]=chkvar-final,
// W[5]=dbg invariant bits.
#define OFF_FLAG  0
#define OFF_WTS   16
#define OFF_SUMS  (OFF_WTS + WT_TOTAL)      // 41,744
#define OFF_CNT   (OFF_SUMS + NVAR*64)      // 3,241,744
#define OFF_CUR0  (OFF_CNT + NVAR)          // 3,291,744 (fp32, B*S*64)
#define OFF_CUR1  (OFF_CUR0 + BB*SS*DD)     // 20,068,960 (fp32, B*S*64)
#define WS_NEED_BYTES ((size_t)(OFF_CUR1 + BB*SS*DD) * 4)

__device__ __forceinline__ float bf2f(uint_t h) {
    union { uint_t u; float f; } v; v.u = h << 16; return v.f;
}
__device__ __forceinline__ float frcp(float x) { return __builtin_amdgcn_rcpf(x); }
__device__ __forceinline__ float sigm(float x) { return frcp(1.f + __expf(-x)); }
__device__ __forceinline__ float ftanh(float x) {
    return 1.f - 2.f * frcp(__expf(2.f * x) + 1.f);
}
__device__ __forceinline__ float fetchv(const void* p, int j, bool bf) {
    return bf ? bf2f(((const ushort_t*)p)[j]) : ((const float*)p)[j];
}

// ---------------------------------------------------------------- k_sniff
// fp32 data reinterpreted as bf16: ~47% |x|>100-or-NaN. bf16 N(0,0.02) never.
__global__ void k_sniff(const ushort_t* __restrict__ tab, int* __restrict__ flag) {
    if (threadIdx.x == 0 && blockIdx.x == 0) {
        int insane = 0;
        for (int i = 0; i < 128; i++) {
            float a = fabsf(bf2f(tab[i]));
            if (!(a <= 100.f)) insane++;
        }
        *flag = (insane <= 8) ? 1 : 0;   // 1 => inputs are bf16
    }
}

// ---------------------------------------------------------------- k_cvt
__global__ __launch_bounds__(256) void k_cvt(
    const void* __restrict__ gk, const void* __restrict__ grk,
    const void* __restrict__ gb, const void* __restrict__ lw,
    const int* __restrict__ flag, float* __restrict__ wts)
{
    const bool bf = (*flag) != 0;
    int i = blockIdx.x * 256 + threadIdx.x;
    if (i < 24576)          wts[i] = fetchv(gk, i, bf);
    else if (i < 36864)     wts[i] = fetchv(grk, i - 24576, bf);
    else if (i < 37632)     wts[i] = fetchv(gb, i - 36864, bf);
    else if (i < WT_TOTAL)  wts[i] = fetchv(lw, i - 37632, bf);
}

// ---------------------------------------------------------------- k_gru (fused)
// One (batch, dir) per 192-thread block. Threads 0..95: recurrent dot col j;
// threads 0..31 apply gates, write h/curout (fp32). Threads 96..191: input
// projection producers 2 steps ahead; 96..159 gather+mask x 3 ahead.
template<int LAYER>
__global__ __launch_bounds__(192, 1) void k_gru(
    const void* __restrict__ table, const int* __restrict__ gm,
    const int* __restrict__ slen, const float* __restrict__ wts,
    const int* __restrict__ flagp,
    const float* __restrict__ curin,   // LAYER==1 input
    float* __restrict__ curout)
{
    const int bb = blockIdx.x >> 1, dir = blockIdx.x & 1;
    const int j = threadIdx.x;
    const bool bfin = (*flagp) != 0;
    const int myslen = slen[bb];

    const float* Km  = wts + WT_KERN + (size_t)(LAYER*2+dir)*(DD*GG);
    const float* R   = wts + WT_REC  + (size_t)(LAYER*2+dir)*(UU*GG);
    const float* bin = wts + WT_BIAS + (size_t)((LAYER*2+dir)*2 + 0)*GG;
    const float* brc = wts + WT_BIAS + (size_t)((LAYER*2+dir)*2 + 1)*GG;

    __shared__ __align__(16) float h_sh[UU];
    __shared__ float mi_sh[GG];
    __shared__ float mx_sh[3][GG];
    __shared__ float xs_sh[2][DD];

    float Rc[UU]; float bj = 0.f;
    float Kc[DD]; float bpj = 0.f;
    if (j < GG) {
#pragma unroll
        for (int k = 0; k < UU; k++) Rc[k] = R[k*GG + j];
        bj = brc[j];
    } else {
        const int pj = j - 96;
#pragma unroll
        for (int k = 0; k < DD; k++) Kc[k] = Km[k*GG + pj];
        bpj = bin[pj];
    }
    if (j < UU) h_sh[j] = 0.f;
    __syncthreads();

    const ushort_t* tab16 = (const ushort_t*)table;
    const float*    tab32 = (const float*)table;

    for (int su = 0; su <= SS + 2; su++) {
        float mi = bj, px = bpj, xv = 0.f;
        if (j < GG) {
            if (su >= 3) {
                float hr[UU];
#pragma unroll
                for (int kq = 0; kq < 8; kq++) {
                    float4 hv = reinterpret_cast<const float4*>(h_sh)[kq];
                    hr[kq*4]=hv.x; hr[kq*4+1]=hv.y; hr[kq*4+2]=hv.z; hr[kq*4+3]=hv.w;
                }
#pragma unroll
                for (int k = 0; k < UU; k++) mi = fmaf(hr[k], Rc[k], mi);
                mi_sh[j] = mi;
            }
        } else {
            if (su >= 1 && su <= SS) {
                const float* xs = xs_sh[(su-1)&1];
#pragma unroll
                for (int k = 0; k < DD; k++) px = fmaf(xs[k], Kc[k], px);
            }
            const int lk = j - 96;
            if (lk < DD && su < SS) {
                const int p3 = dir ? (SS-1-su) : su;
                if (p3 < myslen) {
                    if (LAYER == 0) {
                        const int idx = gm[(size_t)bb*SS + p3];
                        xv = bfin ? bf2f(tab16[(size_t)idx*DD + lk])
                                  : tab32[(size_t)idx*DD + lk];
                    } else {
                        xv = curin[((size_t)bb*SS + p3)*DD + lk];
                    }
                }
            }
        }
        __syncthreads();   // B1
        if (j < UU) {
            if (su >= 3) {
                const int s = su - 3;
                const int p = dir ? (SS-1-s) : s;
                const float* mrow = mx_sh[su % 3];
                const float z  = sigm(mrow[j]      + mi_sh[j]);
                const float r  = sigm(mrow[32 + j] + mi_sh[32 + j]);
                const float th = ftanh(mrow[64 + j] + r * mi_sh[64 + j]);
                const float hn = th + z * (h_sh[j] - th);
                h_sh[j] = hn;
                curout[((size_t)bb*SS + p)*DD + dir*UU + j] = hn;
            }
        } else if (j >= 96) {
            if (su >= 1 && su <= SS) mx_sh[(su-1) % 3][j-96] = px;
            const int lk = j - 96;
            if (lk < DD && su < SS) xs_sh[su & 1][lk] = xv;
        }
        __syncthreads();   // B2
    }
}

// ---------------------------------------------------------------- k_selfchk0
// Textbook serial layer-0 GRU for batch 0 (dir = blockIdx.x) vs pipeline cur0.
__global__ __launch_bounds__(128, 1) void k_selfchk0(
    const void* __restrict__ table, const int* __restrict__ gm,
    const int* __restrict__ slen, const float* __restrict__ wts,
    const int* __restrict__ flagp, const float* __restrict__ cur0,
    float* __restrict__ Wslot)
{
    const int dir = blockIdx.x;
    const int j = threadIdx.x;
    const bool bfin = (*flagp) != 0;
    const int sl0 = slen[0];
    const float* Km  = wts + WT_KERN + (size_t)dir*(DD*GG);
    const float* R   = wts + WT_REC  + (size_t)dir*(UU*GG);
    const float* bin = wts + WT_BIAS + (size_t)(dir*2 + 0)*GG;
    const float* brc = wts + WT_BIAS + (size_t)(dir*2 + 1)*GG;

    float Kc[DD], Rc[UU], bj = 0.f, cj = 0.f;
    if (j < GG) {
#pragma unroll
        for (int k = 0; k < DD; k++) Kc[k] = Km[k*GG + j];
#pragma unroll
        for (int k = 0; k < UU; k++) Rc[k] = R[k*GG + j];
        bj = bin[j]; cj = brc[j];
    }
    __shared__ float h[UU], xs[DD], mxs[GG], mis[GG];
    __shared__ uint_t dmax_sh;
    if (j < UU) h[j] = 0.f;
    if (j == 0) dmax_sh = 0u;
    __syncthreads();

    const ushort_t* t16 = (const ushort_t*)table;
    const float*    t32 = (const float*)table;

    for (int t = 0; t < SS; t++) {
        const int p = dir ? (SS-1-t) : t;
        if (j < DD) {
            float xv = 0.f;
            if (p < sl0) {
                const int idx = gm[p];   // batch 0
                xv = bfin ? bf2f(t16[(size_t)idx*DD + j]) : t32[(size_t)idx*DD + j];
            }
            xs[j] = xv;
        }
        __syncthreads();
        if (j < GG) {
            float mx = bj, mi = cj;
#pragma unroll
            for (int k = 0; k < DD; k++) mx = fmaf(xs[k], Kc[k], mx);
#pragma unroll
            for (int k = 0; k < UU; k++) mi = fmaf(h[k], Rc[k], mi);
            mxs[j] = mx; mis[j] = mi;
        }
        __syncthreads();
        if (j < UU) {
            const float z  = sigm(mxs[j] + mis[j]);
            const float r  = sigm(mxs[32+j] + mis[32+j]);
            const float th = ftanh(mxs[64+j] + r*mis[64+j]);
            const float hn = th + z*(h[j]-th);
            const float rf = cur0[(size_t)p*DD + dir*UU + j];
            atomicMax(&dmax_sh, __float_as_uint(fabsf(hn - rf)));
            h[j] = hn;
        }
        __syncthreads();
    }
    if (j == 0) atomicMax((uint_t*)Wslot, dmax_sh);
}

// ---------------------------------------------------------------- k_chkvar
// Brute-force recompute ve[v*] for v*=tvi[0]; compare vs means.
__global__ __launch_bounds__(64, 1) void k_chkvar(
    const float* __restrict__ cur, const int* __restrict__ vbti,
    const int* __restrict__ tvi, const float* __restrict__ means,
    float* __restrict__ Wslot)
{
    const int j = threadIdx.x;
    __shared__ int tv[64], vb[64];
    __shared__ float cnt_sh;
    const int vstar = tvi[0];
    float sum = 0.f, cnt = 0.f;
    for (int base = 0; base < NEDGE; base += 64) {
        const int me = base + j;
        tv[j] = (me < NEDGE) ? tvi[me] : -1;
        vb[j] = (me < NEDGE) ? vbti[me] : 0;
        __syncthreads();
        for (int q = 0; q < 64; q++) {
            if (tv[q] == vstar) {
                sum += cur[(size_t)vb[q]*64 + j];
                if (j == 0) cnt += 1.f;
            }
        }
        __syncthreads();
    }
    if (j == 0) cnt_sh = cnt;
    __syncthreads();
    const float ve = sum / fmaxf(cnt_sh, 1.f);
    const float d = fabsf(ve - means[(size_t)vstar*64 + j]);
    atomicMax((uint_t*)Wslot, __float_as_uint(d));
}

// ---------------------------------------------------------------- scatter / mean / class
__global__ __launch_bounds__(256) void k_scatter_sum(
    const float* __restrict__ cur, const int* __restrict__ vbti,
    const int* __restrict__ tvi, float* __restrict__ sums, float* __restrict__ cnt)
{
    const int lane = threadIdx.x & 63;
    const int base = blockIdx.x * 4 + (threadIdx.x >> 6);
    for (int e = base; e < NEDGE; e += gridDim.x * 4) {
        const int tok = vbti[e];
        const int var = tvi[e];
        const float v = cur[(size_t)tok * 64 + lane];
        atomicAdd(&sums[(size_t)var * 64 + lane], v);
        if (lane == 0) atomicAdd(&cnt[var], 1.f);
    }
}

__global__ __launch_bounds__(256) void k_scatter_back(
    const float* __restrict__ means, const int* __restrict__ vbti,
    const int* __restrict__ tvi, float* __restrict__ cur)
{
    const int lane = threadIdx.x & 63;
    const int base = blockIdx.x * 4 + (threadIdx.x >> 6);
    for (int e = base; e < NEDGE; e += gridDim.x * 4) {
        const int tok = vbti[e];
        const int var = tvi[e];
        const float m = means[(size_t)var * 64 + lane];
        atomicAdd(&cur[(size_t)tok * 64 + lane], m);
    }
}

template<bool WRITE_OUT>
__global__ __launch_bounds__(256) void k_mean(
    float* __restrict__ sums, const float* __restrict__ cnt, float* __restrict__ out)
{
    const int i = blockIdx.x * 256 + threadIdx.x;
    if (i < NVAR * 64) {
        const float c = fmaxf(cnt[i >> 6], 1.f);
        const float v = sums[i] / c;
        sums[i] = v;                       // keep means for downstream
        if (WRITE_OUT) out[i] = v;         // fp32 output
    }
}

__global__ __launch_bounds__(256) void k_class(
    const float* __restrict__ means, const float* __restrict__ w,
    float* __restrict__ out)
{
    __shared__ float Wl[64 * 64];
    for (int i = threadIdx.x; i < 4096; i += 256) Wl[i] = w[i];
    __syncthreads();
    const int gid = blockIdx.x * 256 + threadIdx.x;
    if (gid < NVAR * 64) {
        const int v = gid >> 6, jj = gid & 63;
        const float* mv = means + (size_t)v * 64;
        float acc = 0.f;
#pragma unroll
        for (int k = 0; k < 64; k++) acc = fmaf(mv[k], Wl[k * 64 + jj], acc);
        out[(size_t)NVAR * 64 + gid] = acc;   // fp32 output
    }
}

// ---------------------------------------------------------------- diagnostics
__global__ void k_err(float* out, int prio) { out[0] = (float)(131072 << prio); }

__global__ __launch_bounds__(256) void k_dbg(
    int* __restrict__ dbgbad, const int* __restrict__ flag,
    const int* __restrict__ slen, const int* __restrict__ gm,
    const float* __restrict__ cur0, const float* __restrict__ cur1,
    const float* __restrict__ means, const float* __restrict__ cnt)
{
    __shared__ int bad[4];
    __shared__ float cntsum;
    const int t = threadIdx.x;
    if (t < 4) bad[t] = 0;
    if (t == 0) cntsum = 0.f;
    __syncthreads();
    if (t < BB) { int v = slen[t]; if (v < 1 || v > SS) atomicAdd(&bad[0], 1); }
    { int g = gm[t * 1021]; if (g < 0 || g >= VOCAB) atomicAdd(&bad[1], 1); }
    { float v = fabsf(cur0[(size_t)t * 65521]);
      if (!(v >= 1e-9f && v <= 100.f)) atomicAdd(&bad[2], 1); }
    { float v = fabsf(cur1[(size_t)t * 65521]);
      if (!(v >= 1e-9f && v <= 100.f)) atomicAdd(&bad[2], 1); }
    { float v = fabsf(means[(size_t)t * 12497]);
      if (!(v >= 1e-9f && v <= 100.f)) atomicAdd(&bad[3], 1); }
    atomicAdd(&cntsum, cnt[t * 195]);
    __syncthreads();
    if (t == 0) {
        const int f = *flag;
        int b = 0;
        if (f != 0 && f != 1) b = 1;
        else if (bad[0]) b = 1;
        else if (bad[1]) b = 1;
        else if (bad[2] > 96) b = 1;
        else if (bad[3] > 48) b = 1;
        else if (cntsum < 256.f || cntsum > 51200.f) b = 1;
        if (b) atomicOr(dbgbad, 1);
    }
}

// k_probe: writes ONLY on failure: out[0] = 2048*(1+bits)
//   bits: b0=selfchk0  b1=consist-var  b2=final-var  b3=dbg  b4=flag(bf16 in)
__global__ void k_probe(float* __restrict__ out, const float* __restrict__ W) {
    if (threadIdx.x != 0 || blockIdx.x != 0) return;
    const uint_t* Wu = (const uint_t*)W;
    const int flag = ((const int*)W)[0];
    const float d0 = __uint_as_float(Wu[1]);
    const float d1 = __uint_as_float(Wu[2]);
    const float d2 = __uint_as_float(Wu[3]);
    const int dbgbad = ((const int*)W)[5];
    int bits = 0;
    if (d0 > 1e-4f) bits |= 1;
    if (d1 > 1e-2f) bits |= 2;
    if (d2 > 1e-2f) bits |= 4;
    if (dbgbad)     bits |= 8;
    if (flag)       bits |= 16;
    if (bits & 15) out[0] = 2048.f * (float)(1 + bits);
}

// ---------------------------------------------------------------- launch
extern "C" void kernel_launch(void* const* d_in, const int* in_sizes, int n_in,
                              void* d_out, int out_size, void* d_ws, size_t ws_size,
                              hipStream_t stream) {
    const void* table = d_in[0];
    const void* gk    = d_in[1];
    const void* grk   = d_in[2];
    const void* gb    = d_in[3];
    const void* lw    = d_in[4];
    const int* gm   = (const int*)d_in[5];
    const int* slen = (const int*)d_in[6];
    const int* vbti = (const int*)d_in[7];
    const int* tvi  = (const int*)d_in[8];
    float* out = (float*)d_out;                       // fp32 output (H2)

    if (ws_size < WS_NEED_BYTES) { k_err<<<1, 1, 0, stream>>>(out, 0); return; }
    if (n_in != 10)              { k_err<<<1, 1, 0, stream>>>(out, 1); return; }
    if (in_sizes[0] != VOCAB*DD || in_sizes[5] != BB*SS || in_sizes[6] != BB ||
        in_sizes[7] != NEDGE || in_sizes[8] != NEDGE) {
        k_err<<<1, 1, 0, stream>>>(out, 2); return;
    }
    if (out_size != 2*NVAR*64)   { k_err<<<1, 1, 0, stream>>>(out, 3); return; }

    float* W = (float*)d_ws;
    int*   flag = (int*)(W + OFF_FLAG);
    float* wts  = W + OFF_WTS;
    float* sums = W + OFF_SUMS;
    float* cnt  = W + OFF_CNT;
    float* cur0 = W + OFF_CUR0;
    float* cur1 = W + OFF_CUR1;

    hipMemsetAsync(W + 1, 0, 8 * sizeof(float), stream);   // verdict slots
    k_sniff<<<1, 64, 0, stream>>>((const ushort_t*)table, flag);
    k_cvt<<<163, 256, 0, stream>>>(gk, grk, gb, lw, flag, wts);

    // ----- layer 0
    k_gru<0><<<64, 192, 0, stream>>>(table, gm, slen, wts, flag, nullptr, cur0);
    k_selfchk0<<<2, 128, 0, stream>>>(table, gm, slen, wts, flag, cur0, W + 1);

    // ----- consistency layer
    hipMemsetAsync(sums, 0, (size_t)(NVAR * 64 + NVAR) * sizeof(float), stream);
    k_scatter_sum<<<2048, 256, 0, stream>>>(cur0, vbti, tvi, sums, cnt);
    k_mean<false><<<12500, 256, 0, stream>>>(sums, cnt, nullptr);
    k_chkvar<<<1, 64, 0, stream>>>(cur0, vbti, tvi, sums, W + 2);
    k_scatter_back<<<2048, 256, 0, stream>>>(sums, vbti, tvi, cur0);

    // ----- layer 1
    k_gru<1><<<64, 192, 0, stream>>>(table, gm, slen, wts, flag, cur0, cur1);

    // ----- final variable embeddings + classification
    hipMemsetAsync(sums, 0, (size_t)(NVAR * 64 + NVAR) * sizeof(float), stream);
    k_scatter_sum<<<2048, 256, 0, stream>>>(cur1, vbti, tvi, sums, cnt);
    k_mean<true><<<12500, 256, 0, stream>>>(sums, cnt, out);
    k_chkvar<<<1, 64, 0, stream>>>(cur1, vbti, tvi, sums, W + 3);
    k_class<<<12500, 256, 0, stream>>>(sums, wts + WT_LW, out);

    // ----- invariants + consolidated probe (no-op when healthy)
    k_dbg<<<1, 256, 0, stream>>>((int*)(W + 5), flag, slen, gm, cur0, cur1, sums, cnt);
    k_probe<<<1, 1, 0, stream>>>(out, W);
}

// Round 8
// 11894.791 us; speedup vs baseline: 6.9494x; 6.9494x over previous
//
#include <hip/hip_runtime.h>
#include <hip/hip_bf16.h>

typedef unsigned short ushort_t;
typedef unsigned int uint_t;

// Problem constants (fixed shapes)
#define BB    32
#define SS    8192
#define DD    64
#define UU    32
#define GG    96        // 3U
#define NEDGE 500000
#define NVAR  50000
#define VOCAB 10000

// fp32 weight cache sub-layout
#define WT_KERN   0                         // [2][2][64][96] = 24576
#define WT_REC    24576                     // [2][2][32][96] = 12288
#define WT_BIAS   36864                     // [2][2][2][96]  = 768
#define WT_LW     37632                     // [64][64]       = 4096
#define WT_TOTAL  41728

// ws layout (float offsets). Total = 147,384,704 bytes ~= 140.6 MiB.
#define OFF_FLAG  0
#define OFF_WTS   16
#define OFF_SUMS  (OFF_WTS + WT_TOTAL)      // 41,744
#define OFF_CNT   (OFF_SUMS + NVAR*64)      // 3,241,744
#define OFF_CUR0  (OFF_CNT + NVAR)          // 3,291,744 (fp32, B*S*64)
#define OFF_CUR1  (OFF_CUR0 + BB*SS*DD)     // 20,068,960 (fp32, B*S*64)
#define WS_NEED_BYTES ((size_t)(OFF_CUR1 + BB*SS*DD) * 4)

__device__ __forceinline__ float bf2f(uint_t h) {
    union { uint_t u; float f; } v; v.u = h << 16; return v.f;
}
__device__ __forceinline__ float frcp(float x) { return __builtin_amdgcn_rcpf(x); }
__device__ __forceinline__ float sigm(float x) { return frcp(1.f + __expf(-x)); }
__device__ __forceinline__ float ftanh(float x) {
    return 1.f - 2.f * frcp(__expf(2.f * x) + 1.f);
}
__device__ __forceinline__ float fetchv(const void* p, int j, bool bf) {
    return bf ? bf2f(((const ushort_t*)p)[j]) : ((const float*)p)[j];
}

// ---------------------------------------------------------------- k_sniff
// fp32 data reinterpreted as bf16: ~47% |x|>100-or-NaN. bf16 N(0,0.02) never.
__global__ void k_sniff(const ushort_t* __restrict__ tab, int* __restrict__ flag) {
    if (threadIdx.x == 0 && blockIdx.x == 0) {
        int insane = 0;
        for (int i = 0; i < 128; i++) {
            float a = fabsf(bf2f(tab[i]));
            if (!(a <= 100.f)) insane++;
        }
        *flag = (insane <= 8) ? 1 : 0;   // 1 => inputs are bf16
    }
}

// ---------------------------------------------------------------- k_cvt
__global__ __launch_bounds__(256) void k_cvt(
    const void* __restrict__ gk, const void* __restrict__ grk,
    const void* __restrict__ gb, const void* __restrict__ lw,
    const int* __restrict__ flag, float* __restrict__ wts)
{
    const bool bf = (*flag) != 0;
    int i = blockIdx.x * 256 + threadIdx.x;
    if (i < 24576)          wts[i] = fetchv(gk, i, bf);
    else if (i < 36864)     wts[i] = fetchv(grk, i - 24576, bf);
    else if (i < 37632)     wts[i] = fetchv(gb, i - 36864, bf);
    else if (i < WT_TOTAL)  wts[i] = fetchv(lw, i - 37632, bf);
}

// ---------------------------------------------------------------- k_gru (fused)
// One (batch, dir) per 192-thread block. Threads 0..95: recurrent dot col j;
// threads 0..31 apply gates, write h/curout (fp32). Threads 96..191: input
// projection producers 2 steps ahead; 96..159 gather+mask x 3 ahead.
template<int LAYER>
__global__ __launch_bounds__(192, 1) void k_gru(
    const void* __restrict__ table, const int* __restrict__ gm,
    const int* __restrict__ slen, const float* __restrict__ wts,
    const int* __restrict__ flagp,
    const float* __restrict__ curin,   // LAYER==1 input
    float* __restrict__ curout)
{
    const int bb = blockIdx.x >> 1, dir = blockIdx.x & 1;
    const int j = threadIdx.x;
    const bool bfin = (*flagp) != 0;
    const int myslen = slen[bb];

    const float* Km  = wts + WT_KERN + (size_t)(LAYER*2+dir)*(DD*GG);
    const float* R   = wts + WT_REC  + (size_t)(LAYER*2+dir)*(UU*GG);
    const float* bin = wts + WT_BIAS + (size_t)((LAYER*2+dir)*2 + 0)*GG;
    const float* brc = wts + WT_BIAS + (size_t)((LAYER*2+dir)*2 + 1)*GG;

    __shared__ __align__(16) float h_sh[UU];
    __shared__ float mi_sh[GG];
    __shared__ float mx_sh[3][GG];
    __shared__ float xs_sh[2][DD];

    float Rc[UU]; float bj = 0.f;
    float Kc[DD]; float bpj = 0.f;
    if (j < GG) {
#pragma unroll
        for (int k = 0; k < UU; k++) Rc[k] = R[k*GG + j];
        bj = brc[j];
    } else {
        const int pj = j - 96;
#pragma unroll
        for (int k = 0; k < DD; k++) Kc[k] = Km[k*GG + pj];
        bpj = bin[pj];
    }
    if (j < UU) h_sh[j] = 0.f;
    __syncthreads();

    const ushort_t* tab16 = (const ushort_t*)table;
    const float*    tab32 = (const float*)table;

    for (int su = 0; su <= SS + 2; su++) {
        float mi = bj, px = bpj, xv = 0.f;
        if (j < GG) {
            if (su >= 3) {
                float hr[UU];
#pragma unroll
                for (int kq = 0; kq < 8; kq++) {
                    float4 hv = reinterpret_cast<const float4*>(h_sh)[kq];
                    hr[kq*4]=hv.x; hr[kq*4+1]=hv.y; hr[kq*4+2]=hv.z; hr[kq*4+3]=hv.w;
                }
#pragma unroll
                for (int k = 0; k < UU; k++) mi = fmaf(hr[k], Rc[k], mi);
                mi_sh[j] = mi;
            }
        } else {
            if (su >= 1 && su <= SS) {
                const float* xs = xs_sh[(su-1)&1];
#pragma unroll
                for (int k = 0; k < DD; k++) px = fmaf(xs[k], Kc[k], px);
            }
            const int lk = j - 96;
            if (lk < DD && su < SS) {
                const int p3 = dir ? (SS-1-su) : su;
                if (p3 < myslen) {
                    if (LAYER == 0) {
                        const int idx = gm[(size_t)bb*SS + p3];
                        xv = bfin ? bf2f(tab16[(size_t)idx*DD + lk])
                                  : tab32[(size_t)idx*DD + lk];
                    } else {
                        xv = curin[((size_t)bb*SS + p3)*DD + lk];
                    }
                }
            }
        }
        __syncthreads();   // B1
        if (j < UU) {
            if (su >= 3) {
                const int s = su - 3;
                const int p = dir ? (SS-1-s) : s;
                const float* mrow = mx_sh[su % 3];
                const float z  = sigm(mrow[j]      + mi_sh[j]);
                const float r  = sigm(mrow[32 + j] + mi_sh[32 + j]);
                const float th = ftanh(mrow[64 + j] + r * mi_sh[64 + j]);
                const float hn = th + z * (h_sh[j] - th);
                h_sh[j] = hn;
                curout[((size_t)bb*SS + p)*DD + dir*UU + j] = hn;
            }
        } else if (j >= 96) {
            if (su >= 1 && su <= SS) mx_sh[(su-1) % 3][j-96] = px;
            const int lk = j - 96;
            if (lk < DD && su < SS) xs_sh[su & 1][lk] = xv;
        }
        __syncthreads();   // B2
    }
}

// ---------------------------------------------------------------- scatter / mean / class
__global__ __launch_bounds__(256) void k_scatter_sum(
    const float* __restrict__ cur, const int* __restrict__ vbti,
    const int* __restrict__ tvi, float* __restrict__ sums, float* __restrict__ cnt)
{
    const int lane = threadIdx.x & 63;
    const int base = blockIdx.x * 4 + (threadIdx.x >> 6);
    for (int e = base; e < NEDGE; e += gridDim.x * 4) {
        const int tok = vbti[e];
        const int var = tvi[e];
        const float v = cur[(size_t)tok * 64 + lane];
        atomicAdd(&sums[(size_t)var * 64 + lane], v);
        if (lane == 0) atomicAdd(&cnt[var], 1.f);
    }
}

__global__ __launch_bounds__(256) void k_scatter_back(
    const float* __restrict__ means, const int* __restrict__ vbti,
    const int* __restrict__ tvi, float* __restrict__ cur)
{
    const int lane = threadIdx.x & 63;
    const int base = blockIdx.x * 4 + (threadIdx.x >> 6);
    for (int e = base; e < NEDGE; e += gridDim.x * 4) {
        const int tok = vbti[e];
        const int var = tvi[e];
        const float m = means[(size_t)var * 64 + lane];
        atomicAdd(&cur[(size_t)tok * 64 + lane], m);
    }
}

template<bool WRITE_OUT>
__global__ __launch_bounds__(256) void k_mean(
    float* __restrict__ sums, const float* __restrict__ cnt, float* __restrict__ out)
{
    const int i = blockIdx.x * 256 + threadIdx.x;
    if (i < NVAR * 64) {
        const float c = fmaxf(cnt[i >> 6], 1.f);
        const float v = sums[i] / c;
        sums[i] = v;                       // keep means for downstream
        if (WRITE_OUT) out[i] = v;         // fp32 output
    }
}

__global__ __launch_bounds__(256) void k_class(
    const float* __restrict__ means, const float* __restrict__ w,
    float* __restrict__ out)
{
    __shared__ float Wl[64 * 64];
    for (int i = threadIdx.x; i < 4096; i += 256) Wl[i] = w[i];
    __syncthreads();
    const int gid = blockIdx.x * 256 + threadIdx.x;
    if (gid < NVAR * 64) {
        const int v = gid >> 6, jj = gid & 63;
        const float* mv = means + (size_t)v * 64;
        float acc = 0.f;
#pragma unroll
        for (int k = 0; k < 64; k++) acc = fmaf(mv[k], Wl[k * 64 + jj], acc);
        out[(size_t)NVAR * 64 + gid] = acc;   // fp32 output
    }
}

// ---------------------------------------------------------------- k_err (host-guard channel)
__global__ void k_err(float* out, int prio) { out[0] = (float)(131072 << prio); }

// ---------------------------------------------------------------- launch
extern "C" void kernel_launch(void* const* d_in, const int* in_sizes, int n_in,
                              void* d_out, int out_size, void* d_ws, size_t ws_size,
                              hipStream_t stream) {
    const void* table = d_in[0];
    const void* gk    = d_in[1];
    const void* grk   = d_in[2];
    const void* gb    = d_in[3];
    const void* lw    = d_in[4];
    const int* gm   = (const int*)d_in[5];
    const int* slen = (const int*)d_in[6];
    const int* vbti = (const int*)d_in[7];
    const int* tvi  = (const int*)d_in[8];
    float* out = (float*)d_out;                       // fp32 output (verified r7)

    if (ws_size < WS_NEED_BYTES) { k_err<<<1, 1, 0, stream>>>(out, 0); return; }
    if (n_in != 10)              { k_err<<<1, 1, 0, stream>>>(out, 1); return; }
    if (in_sizes[0] != VOCAB*DD || in_sizes[5] != BB*SS || in_sizes[6] != BB ||
        in_sizes[7] != NEDGE || in_sizes[8] != NEDGE) {
        k_err<<<1, 1, 0, stream>>>(out, 2); return;
    }
    if (out_size != 2*NVAR*64)   { k_err<<<1, 1, 0, stream>>>(out, 3); return; }

    float* W = (float*)d_ws;
    int*   flag = (int*)(W + OFF_FLAG);
    float* wts  = W + OFF_WTS;
    float* sums = W + OFF_SUMS;
    float* cnt  = W + OFF_CNT;
    float* cur0 = W + OFF_CUR0;
    float* cur1 = W + OFF_CUR1;

    k_sniff<<<1, 64, 0, stream>>>((const ushort_t*)table, flag);
    k_cvt<<<163, 256, 0, stream>>>(gk, grk, gb, lw, flag, wts);

    // ----- layer 0
    k_gru<0><<<64, 192, 0, stream>>>(table, gm, slen, wts, flag, nullptr, cur0);

    // ----- consistency layer
    hipMemsetAsync(sums, 0, (size_t)(NVAR * 64 + NVAR) * sizeof(float), stream);
    k_scatter_sum<<<2048, 256, 0, stream>>>(cur0, vbti, tvi, sums, cnt);
    k_mean<false><<<12500, 256, 0, stream>>>(sums, cnt, nullptr);
    k_scatter_back<<<2048, 256, 0, stream>>>(sums, vbti, tvi, cur0);

    // ----- layer 1
    k_gru<1><<<64, 192, 0, stream>>>(table, gm, slen, wts, flag, cur0, cur1);

    // ----- final variable embeddings + classification
    hipMemsetAsync(sums, 0, (size_t)(NVAR * 64 + NVAR) * sizeof(float), stream);
    k_scatter_sum<<<2048, 256, 0, stream>>>(cur1, vbti, tvi, sums, cnt);
    k_mean<true><<<12500, 256, 0, stream>>>(sums, cnt, out);
    k_class<<<12500, 256, 0, stream>>>(sums, wts + WT_LW, out);
}

// Round 9
// 11855.373 us; speedup vs baseline: 6.9725x; 1.0033x over previous
//
#include <hip/hip_runtime.h>
#include <hip/hip_bf16.h>

typedef unsigned short ushort_t;
typedef unsigned int uint_t;

// Problem constants (fixed shapes)
#define BB    32
#define SS    8192
#define DD    64
#define UU    32
#define GG    96        // 3U
#define NEDGE 500000
#define NVAR  50000
#define VOCAB 10000

#define CHUNK 16
#define NCH   (SS / CHUNK)   // 512

// fp32 weight cache sub-layout
#define WT_KERN   0                         // [2][2][64][96] = 24576
#define WT_REC    24576                     // [2][2][32][96] = 12288
#define WT_BIAS   36864                     // [2][2][2][96]  = 768
#define WT_LW     37632                     // [64][64]       = 4096
#define WT_TOTAL  41728

// ws layout (float offsets). Total = 147,384,704 bytes ~= 140.6 MiB.
#define OFF_FLAG  0
#define OFF_WTS   16
#define OFF_SUMS  (OFF_WTS + WT_TOTAL)      // 41,744
#define OFF_CNT   (OFF_SUMS + NVAR*64)      // 3,241,744
#define OFF_CUR0  (OFF_CNT + NVAR)          // 3,291,744 (fp32, B*S*64)
#define OFF_CUR1  (OFF_CUR0 + BB*SS*DD)     // 20,068,960 (fp32, B*S*64)
#define WS_NEED_BYTES ((size_t)(OFF_CUR1 + BB*SS*DD) * 4)

__device__ __forceinline__ float bf2f(uint_t h) {
    union { uint_t u; float f; } v; v.u = h << 16; return v.f;
}
__device__ __forceinline__ float frcp(float x) { return __builtin_amdgcn_rcpf(x); }
__device__ __forceinline__ float sigm(float x) { return frcp(1.f + __expf(-x)); }
__device__ __forceinline__ float ftanh(float x) {
    return 1.f - 2.f * frcp(__expf(2.f * x) + 1.f);
}
__device__ __forceinline__ float fetchv(const void* p, int j, bool bf) {
    return bf ? bf2f(((const ushort_t*)p)[j]) : ((const float*)p)[j];
}

// ---------------------------------------------------------------- k_sniff
// fp32 data reinterpreted as bf16: ~47% |x|>100-or-NaN. bf16 N(0,0.02) never.
__global__ void k_sniff(const ushort_t* __restrict__ tab, int* __restrict__ flag) {
    if (threadIdx.x == 0 && blockIdx.x == 0) {
        int insane = 0;
        for (int i = 0; i < 128; i++) {
            float a = fabsf(bf2f(tab[i]));
            if (!(a <= 100.f)) insane++;
        }
        *flag = (insane <= 8) ? 1 : 0;   // 1 => inputs are bf16
    }
}

// ---------------------------------------------------------------- k_cvt
__global__ __launch_bounds__(256) void k_cvt(
    const void* __restrict__ gk, const void* __restrict__ grk,
    const void* __restrict__ gb, const void* __restrict__ lw,
    const int* __restrict__ flag, float* __restrict__ wts)
{
    const bool bf = (*flag) != 0;
    int i = blockIdx.x * 256 + threadIdx.x;
    if (i < 24576)          wts[i] = fetchv(gk, i, bf);
    else if (i < 36864)     wts[i] = fetchv(grk, i - 24576, bf);
    else if (i < 37632)     wts[i] = fetchv(gb, i - 36864, bf);
    else if (i < WT_TOTAL)  wts[i] = fetchv(lw, i - 37632, bf);
}

// ---------------------------------------------------------------- k_gru (wave-specialized)
// One (batch, dir) per 128-thread block = 2 waves.
//   Wave 0 (consumer): the full recurrence in-wave, NO per-step barriers.
//     Lane u<32: z-dot (wA) + r-dot (wB); lane 32+u: hh-dot (wA, wB=0).
//     Dots exchanged via __shfl_xor(.,32); both halves compute gates
//     redundantly (identical fp32 ops -> identical h). h broadcast via
//     32-float LDS buffer (same-wave, lgkmcnt only).
//   Wave 1 (producer): mx = x@K + b_in for a 16-step chunk into a
//     double-buffered LDS ring; x gathered+masked. One barrier per chunk.
// Both waves execute exactly NCH+1 barriers (divergent placement is legal
// on CDNA: s_barrier counts waves, not program counters).
template<int LAYER>
__global__ __launch_bounds__(128, 1) void k_gru(
    const void* __restrict__ table, const int* __restrict__ gm,
    const int* __restrict__ slen, const float* __restrict__ wts,
    const int* __restrict__ flagp,
    const float* __restrict__ curin,   // LAYER==1 input
    float* __restrict__ curout)
{
    const int bb = blockIdx.x >> 1, dir = blockIdx.x & 1;
    const int j = threadIdx.x;
    const int wv = j >> 6;         // 0 = consumer wave, 1 = producer wave
    const int ln = j & 63;
    const bool bfin = (*flagp) != 0;
    const int myslen = slen[bb];

    const float* Km  = wts + WT_KERN + (size_t)(LAYER*2+dir)*(DD*GG);
    const float* R   = wts + WT_REC  + (size_t)(LAYER*2+dir)*(UU*GG);
    const float* bin = wts + WT_BIAS + (size_t)((LAYER*2+dir)*2 + 0)*GG;
    const float* brc = wts + WT_BIAS + (size_t)((LAYER*2+dir)*2 + 1)*GG;

    __shared__ __align__(16) float ring[2][CHUNK][GG];   // mx double-buffer
    __shared__ __align__(16) float xbuf[CHUNK][DD];      // producer-local x rows
    __shared__ __align__(16) float hb[UU];               // consumer h broadcast

    const ushort_t* tab16 = (const ushort_t*)table;
    const float*    tab32 = (const float*)table;

    if (wv == 1) {
        // ================= producer wave =================
        float K0[DD], K1[DD];
        const float b0 = bin[ln];
        const float b1 = (ln < 32) ? bin[64 + ln] : 0.f;
#pragma unroll
        for (int k = 0; k < DD; k++) {
            K0[k] = Km[k*GG + ln];
            K1[k] = (ln < 32) ? Km[k*GG + 64 + ln] : 0.f;
        }
        for (int c = 0; c <= NCH; c++) {
            if (c < NCH) {
                // stage x rows for chunk c
                for (int stp = 0; stp < CHUNK; stp++) {
                    const int s = c*CHUNK + stp;
                    const int p = dir ? (SS-1-s) : s;
                    float xv = 0.f;
                    if (p < myslen) {
                        if (LAYER == 0) {
                            const int idx = gm[(size_t)bb*SS + p];
                            xv = bfin ? bf2f(tab16[(size_t)idx*DD + ln])
                                      : tab32[(size_t)idx*DD + ln];
                        } else {
                            xv = curin[((size_t)bb*SS + p)*DD + ln];
                        }
                    }
                    xbuf[stp][ln] = xv;
                }
                // project: lane ln -> col ln (all), col 64+ln (ln<32)
                float* rg = &ring[c & 1][0][0];
                for (int stp = 0; stp < CHUNK; stp++) {
                    float p0 = b0, p1 = b1;
                    const float4* xr = reinterpret_cast<const float4*>(xbuf[stp]);
#pragma unroll
                    for (int q = 0; q < 16; q++) {
                        const float4 xq = xr[q];
                        p0 = fmaf(xq.x, K0[4*q+0], p0); p1 = fmaf(xq.x, K1[4*q+0], p1);
                        p0 = fmaf(xq.y, K0[4*q+1], p0); p1 = fmaf(xq.y, K1[4*q+1], p1);
                        p0 = fmaf(xq.z, K0[4*q+2], p0); p1 = fmaf(xq.z, K1[4*q+2], p1);
                        p0 = fmaf(xq.w, K0[4*q+3], p0); p1 = fmaf(xq.w, K1[4*q+3], p1);
                    }
                    rg[stp*GG + ln] = p0;
                    if (ln < 32) rg[stp*GG + 64 + ln] = p1;
                }
            }
            __syncthreads();
        }
    } else {
        // ================= consumer wave =================
        const int u = ln & 31;
        const int half = ln >> 5;
        const int colA = half ? (64 + u) : u;
        float wA[UU], wB[UU];
        const float bA = brc[colA];
        const float bB = half ? 0.f : brc[32 + u];
#pragma unroll
        for (int k = 0; k < UU; k++) {
            wA[k] = R[k*GG + colA];
            wB[k] = half ? 0.f : R[k*GG + 32 + u];
        }
        float h_own = 0.f;
        float hreg[UU];
#pragma unroll
        for (int k = 0; k < UU; k++) hreg[k] = 0.f;

        for (int c = 0; c <= NCH; c++) {
            if (c > 0) {
                const int c0 = c - 1;
                const float* rg = &ring[c0 & 1][0][0];
                for (int stp = 0; stp < CHUNK; stp++) {
                    const int s = c0*CHUNK + stp;
                    const int p = dir ? (SS-1-s) : s;
                    const float mz = rg[stp*GG + u];
                    const float mr = rg[stp*GG + 32 + u];
                    const float mh = rg[stp*GG + 64 + u];
                    float a = bA, cr = bB;
#pragma unroll
                    for (int k = 0; k < UU; k++) {
                        a  = fmaf(hreg[k], wA[k], a);
                        cr = fmaf(hreg[k], wB[k], cr);
                    }
                    const float ax = __shfl_xor(a, 32);
                    const float cx = __shfl_xor(cr, 32);
                    const float zd = half ? ax : a;    // z-dot
                    const float rd = half ? cx : cr;   // r-dot
                    const float hd = half ? a  : ax;   // hh-dot
                    const float z  = sigm(mz + zd);
                    const float r  = sigm(mr + rd);
                    const float th = ftanh(mh + r * hd);
                    const float hn = th + z * (h_own - th);
                    h_own = hn;
                    if (half == 0) {
                        hb[u] = hn;
                        curout[((size_t)bb*SS + p)*DD + dir*UU + u] = hn;
                    }
#pragma unroll
                    for (int q = 0; q < 8; q++) {
                        const float4 hv = reinterpret_cast<const float4*>(hb)[q];
                        hreg[4*q+0] = hv.x; hreg[4*q+1] = hv.y;
                        hreg[4*q+2] = hv.z; hreg[4*q+3] = hv.w;
                    }
                }
            }
            __syncthreads();
        }
    }
}

// ---------------------------------------------------------------- scatter / mean / class
__global__ __launch_bounds__(256) void k_scatter_sum(
    const float* __restrict__ cur, const int* __restrict__ vbti,
    const int* __restrict__ tvi, float* __restrict__ sums, float* __restrict__ cnt)
{
    const int lane = threadIdx.x & 63;
    const int base = blockIdx.x * 4 + (threadIdx.x >> 6);
    for (int e = base; e < NEDGE; e += gridDim.x * 4) {
        const int tok = vbti[e];
        const int var = tvi[e];
        const float v = cur[(size_t)tok * 64 + lane];
        atomicAdd(&sums[(size_t)var * 64 + lane], v);
        if (lane == 0) atomicAdd(&cnt[var], 1.f);
    }
}

__global__ __launch_bounds__(256) void k_scatter_back(
    const float* __restrict__ means, const int* __restrict__ vbti,
    const int* __restrict__ tvi, float* __restrict__ cur)
{
    const int lane = threadIdx.x & 63;
    const int base = blockIdx.x * 4 + (threadIdx.x >> 6);
    for (int e = base; e < NEDGE; e += gridDim.x * 4) {
        const int tok = vbti[e];
        const int var = tvi[e];
        const float m = means[(size_t)var * 64 + lane];
        atomicAdd(&cur[(size_t)tok * 64 + lane], m);
    }
}

template<bool WRITE_OUT>
__global__ __launch_bounds__(256) void k_mean(
    float* __restrict__ sums, const float* __restrict__ cnt, float* __restrict__ out)
{
    const int i = blockIdx.x * 256 + threadIdx.x;
    if (i < NVAR * 64) {
        const float c = fmaxf(cnt[i >> 6], 1.f);
        const float v = sums[i] / c;
        sums[i] = v;                       // keep means for downstream
        if (WRITE_OUT) out[i] = v;         // fp32 output
    }
}

__global__ __launch_bounds__(256) void k_class(
    const float* __restrict__ means, const float* __restrict__ w,
    float* __restrict__ out)
{
    __shared__ float Wl[64 * 64];
    for (int i = threadIdx.x; i < 4096; i += 256) Wl[i] = w[i];
    __syncthreads();
    const int gid = blockIdx.x * 256 + threadIdx.x;
    if (gid < NVAR * 64) {
        const int v = gid >> 6, jj = gid & 63;
        const float* mv = means + (size_t)v * 64;
        float acc = 0.f;
#pragma unroll
        for (int k = 0; k < 64; k++) acc = fmaf(mv[k], Wl[k * 64 + jj], acc);
        out[(size_t)NVAR * 64 + gid] = acc;   // fp32 output
    }
}

// ---------------------------------------------------------------- k_err (host-guard channel)
__global__ void k_err(float* out, int prio) { out[0] = (float)(131072 << prio); }

// ---------------------------------------------------------------- launch
extern "C" void kernel_launch(void* const* d_in, const int* in_sizes, int n_in,
                              void* d_out, int out_size, void* d_ws, size_t ws_size,
                              hipStream_t stream) {
    const void* table = d_in[0];
    const void* gk    = d_in[1];
    const void* grk   = d_in[2];
    const void* gb    = d_in[3];
    const void* lw    = d_in[4];
    const int* gm   = (const int*)d_in[5];
    const int* slen = (const int*)d_in[6];
    const int* vbti = (const int*)d_in[7];
    const int* tvi  = (const int*)d_in[8];
    float* out = (float*)d_out;                       // fp32 output (verified r7)

    if (ws_size < WS_NEED_BYTES) { k_err<<<1, 1, 0, stream>>>(out, 0); return; }
    if (n_in != 10)              { k_err<<<1, 1, 0, stream>>>(out, 1); return; }
    if (in_sizes[0] != VOCAB*DD || in_sizes[5] != BB*SS || in_sizes[6] != BB ||
        in_sizes[7] != NEDGE || in_sizes[8] != NEDGE) {
        k_err<<<1, 1, 0, stream>>>(out, 2); return;
    }
    if (out_size != 2*NVAR*64)   { k_err<<<1, 1, 0, stream>>>(out, 3); return; }

    float* W = (float*)d_ws;
    int*   flag = (int*)(W + OFF_FLAG);
    float* wts  = W + OFF_WTS;
    float* sums = W + OFF_SUMS;
    float* cnt  = W + OFF_CNT;
    float* cur0 = W + OFF_CUR0;
    float* cur1 = W + OFF_CUR1;

    k_sniff<<<1, 64, 0, stream>>>((const ushort_t*)table, flag);
    k_cvt<<<163, 256, 0, stream>>>(gk, grk, gb, lw, flag, wts);

    // ----- layer 0
    k_gru<0><<<64, 128, 0, stream>>>(table, gm, slen, wts, flag, nullptr, cur0);

    // ----- consistency layer
    hipMemsetAsync(sums, 0, (size_t)(NVAR * 64 + NVAR) * sizeof(float), stream);
    k_scatter_sum<<<2048, 256, 0, stream>>>(cur0, vbti, tvi, sums, cnt);
    k_mean<false><<<12500, 256, 0, stream>>>(sums, cnt, nullptr);
    k_scatter_back<<<2048, 256, 0, stream>>>(sums, vbti, tvi, cur0);

    // ----- layer 1
    k_gru<1><<<64, 128, 0, stream>>>(table, gm, slen, wts, flag, cur0, cur1);

    // ----- final variable embeddings + classification
    hipMemsetAsync(sums, 0, (size_t)(NVAR * 64 + NVAR) * sizeof(float), stream);
    k_scatter_sum<<<2048, 256, 0, stream>>>(cur1, vbti, tvi, sums, cnt);
    k_mean<true><<<12500, 256, 0, stream>>>(sums, cnt, out);
    k_class<<<12500, 256, 0, stream>>>(sums, wts + WT_LW, out);
}